// Round 8
// baseline (139.806 us; speedup 1.0000x reference)
//
#include <hip/hip_runtime.h>

#define NN 1200
#define NE 719400
#define SDIM 4800

typedef __attribute__((ext_vector_type(8))) short bf16x8;
typedef __attribute__((ext_vector_type(4))) short bf16x4;
typedef __attribute__((ext_vector_type(4))) float f32x4;

static __device__ __constant__ int SMAT[16] = {0,1,2,3,1,4,5,6,2,5,7,8,3,6,8,9};

__device__ __forceinline__ float lk(float v) { return v >= 0.f ? v : 0.1f * v; }

#if __has_builtin(__builtin_amdgcn_mfma_f32_16x16x16bf16_1k)
__device__ __forceinline__ f32x4 mfma1616(bf16x4 a, bf16x4 b, f32x4 c) {
    return __builtin_amdgcn_mfma_f32_16x16x16bf16_1k(a, b, c, 0, 0, 0);
}
#else
__device__ __forceinline__ f32x4 mfma1616(bf16x4 a, bf16x4 b, f32x4 c) {
    asm volatile("v_mfma_f32_16x16x16_bf16 %0, %1, %2, %0\n\ts_nop 7\n\ts_nop 7"
                 : "+v"(c) : "v"(a), "v"(b));
    return c;
}
#endif

// split f32 -> bf16 hi (RNE) + bf16 lo (RNE of residual)  [round-3 proven bit-twiddle]
__device__ __forceinline__ void split8(const float* u, bf16x8& hi, bf16x8& lo) {
#pragma unroll
    for (int e = 0; e < 8; e++) {
        unsigned x = __float_as_uint(u[e]);
        unsigned r = x + 0x7FFFu + ((x >> 16) & 1u);
        hi[e] = (short)(r >> 16);
        float hf = __uint_as_float(r & 0xFFFF0000u);
        float s = u[e] - hf;
        unsigned v = __float_as_uint(s);
        unsigned w = v + 0x7FFFu + ((v >> 16) & 1u);
        lo[e] = (short)(w >> 16);
    }
}

__device__ __forceinline__ void split4(const float* u, bf16x4& hi, bf16x4& lo) {
#pragma unroll
    for (int e = 0; e < 4; e++) {
        unsigned x = __float_as_uint(u[e]);
        unsigned r = x + 0x7FFFu + ((x >> 16) & 1u);
        hi[e] = (short)(r >> 16);
        float hf = __uint_as_float(r & 0xFFFF0000u);
        float s = u[e] - hf;
        unsigned v = __float_as_uint(s);
        unsigned w = v + 0x7FFFu + ((v >> 16) & 1u);
        lo[e] = (short)(w >> 16);
    }
}

__device__ __forceinline__ uint2 split2(float a0, float a1) {
    unsigned u0 = __float_as_uint(a0), u1 = __float_as_uint(a1);
    unsigned r0 = u0 + 0x7FFFu + ((u0 >> 16) & 1u);
    unsigned r1 = u1 + 0x7FFFu + ((u1 >> 16) & 1u);
    float h0 = __uint_as_float(r0 & 0xFFFF0000u);
    float h1 = __uint_as_float(r1 & 0xFFFF0000u);
    float s0 = a0 - h0, s1 = a1 - h1;
    unsigned v0 = __float_as_uint(s0), v1 = __float_as_uint(s1);
    unsigned t0 = v0 + 0x7FFFu + ((v0 >> 16) & 1u);
    unsigned t1 = v1 + 0x7FFFu + ((v1 >> 16) & 1u);
    unsigned hi = (r0 >> 16) | (r1 & 0xFFFF0000u);
    unsigned lo = (t0 >> 16) | (t1 & 0xFFFF0000u);
    return make_uint2(hi, lo);
}

// ---------------- prep: We2^T A-frags (16x16x32), We3^T A-frags (16x16x16), cs zero ----
__global__ void k_prep(const float* __restrict__ We2, const float* __restrict__ We3,
                       unsigned* __restrict__ W2F, unsigned* __restrict__ W3F,
                       float* __restrict__ cs) {
    int t = blockIdx.x * 256 + threadIdx.x;
    if (t < 512) {
        int lane = t & 63, ks = (t >> 6) & 1, mt = t >> 7;
        int m = mt * 16 + (lane & 15);
        int kb = ks * 32 + (lane >> 4) * 8;
        unsigned hi[4], lo[4];
#pragma unroll
        for (int p = 0; p < 4; p++) {
            float a0 = We2[(kb + 2 * p) * 64 + m];
            float a1 = We2[(kb + 2 * p + 1) * 64 + m];
            uint2 hl = split2(a0, a1);
            hi[p] = hl.x; lo[p] = hl.y;
        }
        *(uint4*)(W2F + ((mt * 2 + ks) * 2 + 0) * 256 + lane * 4) = make_uint4(hi[0], hi[1], hi[2], hi[3]);
        *(uint4*)(W2F + ((mt * 2 + ks) * 2 + 1) * 256 + lane * 4) = make_uint4(lo[0], lo[1], lo[2], lo[3]);
    } else if (t < 768) {
        int q = t - 512;
        int lane = q & 63, kb = q >> 6;
        int c = lane & 15;
        int k0 = kb * 16 + (lane >> 4) * 4;
        unsigned hi[2], lo[2];
#pragma unroll
        for (int p = 0; p < 2; p++) {
            float a0 = We3[(k0 + 2 * p) * 16 + c];
            float a1 = We3[(k0 + 2 * p + 1) * 16 + c];
            uint2 hl = split2(a0, a1);
            hi[p] = hl.x; lo[p] = hl.y;
        }
        *(uint2*)(W3F + (kb * 2 + 0) * 128 + lane * 2) = make_uint2(hi[0], hi[1]);
        *(uint2*)(W3F + (kb * 2 + 1) * 128 + lane * 2) = make_uint2(lo[0], lo[1]);
    } else if (t < 896) {
        cs[t - 768] = 0.f;
    }
}

// ---------------- GCN stage 1 ----------------
__global__ __launch_bounds__(256) void k_t1(const float* __restrict__ x,
                                            const float* __restrict__ Wg1,
                                            float* __restrict__ t1,
                                            float* __restrict__ cs1) {
    int T = blockIdx.x * 256 + threadIdx.x;
    int c = T & 31, rs = T >> 5;
    float w[6];
#pragma unroll
    for (int k = 0; k < 6; k++) w[k] = Wg1[k * 32 + c];
    float loc = 0.f;
    for (int r = rs; r < NN; r += 304) {
        float acc = 0.f;
#pragma unroll
        for (int k = 0; k < 6; k++) acc = fmaf(x[r * 16 + k], w[k], acc);
        t1[r * 32 + c] = acc;
        loc += acc;
    }
    atomicAdd(&cs1[c], loc);
}

// ---------------- GCN stage 2 ----------------
__global__ __launch_bounds__(256) void k_t2(const float* __restrict__ t1,
                                            const float* __restrict__ cs1,
                                            const float* __restrict__ bg1,
                                            const float* __restrict__ Wg2,
                                            float* __restrict__ t2,
                                            float* __restrict__ cs2) {
    int T = blockIdx.x * 256 + threadIdx.x;
    int c = T & 31, rs = T >> 5;
    const float inv = 1.0f / 1199.0f;
    float p[32], w[32];
#pragma unroll
    for (int k = 0; k < 32; k++) {
        p[k] = fmaf(cs1[k], inv, bg1[k]);
        w[k] = Wg2[k * 32 + c];
    }
    float loc = 0.f;
    for (int r = rs; r < NN; r += 304) {
        float acc = 0.f;
#pragma unroll
        for (int k = 0; k < 32; k++) {
            float h = lk(fmaf(-t1[r * 32 + k], inv, p[k]));
            acc = fmaf(h, w[k], acc);
        }
        t2[r * 32 + c] = acc;
        loc += acc;
    }
    atomicAdd(&cs2[c], loc);
}

// ---------------- GCN stage 3 ----------------
__global__ __launch_bounds__(256) void k_t3(const float* __restrict__ t2,
                                            const float* __restrict__ cs2,
                                            const float* __restrict__ bg2,
                                            const float* __restrict__ Wg3,
                                            float* __restrict__ t3,
                                            float* __restrict__ cs3) {
    int T = blockIdx.x * 256 + threadIdx.x;
    int c = T & 63, rs = T >> 6;
    const float inv = 1.0f / 1199.0f;
    float p[32], w[32];
#pragma unroll
    for (int k = 0; k < 32; k++) {
        p[k] = fmaf(cs2[k], inv, bg2[k]);
        w[k] = Wg3[k * 64 + c];
    }
    float loc = 0.f;
    for (int r = rs; r < NN; r += 152) {
        float acc = 0.f;
#pragma unroll
        for (int k = 0; k < 32; k++) {
            float h = lk(fmaf(-t2[r * 32 + k], inv, p[k]));
            acc = fmaf(h, w[k], acc);
        }
        t3[r * 64 + c] = acc;
        loc += acc;
    }
    atomicAdd(&cs3[c], loc);
}

// ---------------- k_g: h = GCN3 output, g = h @ We1 ----------------
__global__ __launch_bounds__(256) void k_g(const float* __restrict__ t3,
                                           const float* __restrict__ cs3,
                                           const float* __restrict__ bg3,
                                           const float* __restrict__ We1,
                                           float* __restrict__ h_out,
                                           float* __restrict__ g_out) {
    __shared__ float H[32][65];
    __shared__ float W[4096];
    const int tid = threadIdx.x;
    const int r0 = blockIdx.x * 32;
    const float inv = 1.0f / 1199.0f;

    for (int t = tid; t < 1024; t += 256) ((float4*)W)[t] = ((const float4*)We1)[t];
    for (int t = tid; t < 2048; t += 256) {
        int i = t >> 6, c = t & 63;
        int row = r0 + i;
        float v = 0.f;
        if (row < NN) {
            v = fmaf(cs3[c] - t3[row * 64 + c], inv, bg3[c]);
            h_out[row * 64 + c] = v;
        }
        H[i][c] = v;
    }
    __syncthreads();

    int rg = tid >> 3, cg = tid & 7;
    float acc[8] = {};
#pragma unroll 8
    for (int k = 0; k < 64; k++) {
        float a = H[rg][k];
        float4 b0 = *(const float4*)&W[k * 64 + cg * 8];
        float4 b1 = *(const float4*)&W[k * 64 + cg * 8 + 4];
        acc[0] = fmaf(a, b0.x, acc[0]); acc[1] = fmaf(a, b0.y, acc[1]);
        acc[2] = fmaf(a, b0.z, acc[2]); acc[3] = fmaf(a, b0.w, acc[3]);
        acc[4] = fmaf(a, b1.x, acc[4]); acc[5] = fmaf(a, b1.y, acc[5]);
        acc[6] = fmaf(a, b1.z, acc[6]); acc[7] = fmaf(a, b1.w, acc[7]);
    }
    int row = r0 + rg;
    if (row < NN) {
        *(float4*)&g_out[row * 64 + cg * 8]     = make_float4(acc[0], acc[1], acc[2], acc[3]);
        *(float4*)&g_out[row * 64 + cg * 8 + 4] = make_float4(acc[4], acc[5], acc[6], acc[7]);
    }
}

// ---------------- k_vd: node MLP + diagonal Vsym blocks -> S ----------------
__global__ __launch_bounds__(256) void k_vd(const float* __restrict__ h,
                                            const float* __restrict__ Wn1, const float* __restrict__ bn1,
                                            const float* __restrict__ Wn2, const float* __restrict__ bn2,
                                            const float* __restrict__ Wn3, const float* __restrict__ bn3,
                                            float* __restrict__ S) {
    __shared__ float H[32][65];
    __shared__ float N1[32][65];
    __shared__ float WB[4096];
    __shared__ float WC[4096];
    __shared__ float WD[640];
    __shared__ float VD[32][12];
    __shared__ float sb1[64], sb2[64], sb3[16];

    const int tid = threadIdx.x;
    const int r0 = blockIdx.x * 32;

    for (int t = tid; t < 1024; t += 256) {
        ((float4*)WB)[t] = ((const float4*)Wn1)[t];
        ((float4*)WC)[t] = ((const float4*)Wn2)[t];
    }
    for (int t = tid; t < 640; t += 256) WD[t] = Wn3[t];
    if (tid < 64) { sb1[tid] = bn1[tid]; sb2[tid] = bn2[tid]; }
    if (tid < 10) sb3[tid] = bn3[tid];

    for (int t = tid; t < 2048; t += 256) {
        int i = t >> 6, c = t & 63;
        int row = r0 + i;
        H[i][c] = (row < NN) ? h[row * 64 + c] : 0.f;
    }
    __syncthreads();

    int rg = tid >> 3, cg = tid & 7;
    {
        float acc[8] = {};
#pragma unroll 8
        for (int k = 0; k < 64; k++) {
            float a = H[rg][k];
            float4 b0 = *(const float4*)&WB[k * 64 + cg * 8];
            float4 b1 = *(const float4*)&WB[k * 64 + cg * 8 + 4];
            acc[0] = fmaf(a, b0.x, acc[0]); acc[1] = fmaf(a, b0.y, acc[1]);
            acc[2] = fmaf(a, b0.z, acc[2]); acc[3] = fmaf(a, b0.w, acc[3]);
            acc[4] = fmaf(a, b1.x, acc[4]); acc[5] = fmaf(a, b1.y, acc[5]);
            acc[6] = fmaf(a, b1.z, acc[6]); acc[7] = fmaf(a, b1.w, acc[7]);
        }
#pragma unroll
        for (int q = 0; q < 8; q++) N1[rg][cg * 8 + q] = lk(acc[q] + sb1[cg * 8 + q]);
    }
    __syncthreads();
    {
        float acc[8] = {};
#pragma unroll 8
        for (int k = 0; k < 64; k++) {
            float a = N1[rg][k];
            float4 b0 = *(const float4*)&WC[k * 64 + cg * 8];
            float4 b1 = *(const float4*)&WC[k * 64 + cg * 8 + 4];
            acc[0] = fmaf(a, b0.x, acc[0]); acc[1] = fmaf(a, b0.y, acc[1]);
            acc[2] = fmaf(a, b0.z, acc[2]); acc[3] = fmaf(a, b0.w, acc[3]);
            acc[4] = fmaf(a, b1.x, acc[4]); acc[5] = fmaf(a, b1.y, acc[5]);
            acc[6] = fmaf(a, b1.z, acc[6]); acc[7] = fmaf(a, b1.w, acc[7]);
        }
#pragma unroll
        for (int q = 0; q < 8; q++) H[rg][cg * 8 + q] = lk(acc[q] + sb2[cg * 8 + q]);
    }
    __syncthreads();
    for (int t = tid; t < 320; t += 256) {
        int r = t / 10, c = t % 10;
        float acc = sb3[c];
        for (int k = 0; k < 64; k++) acc = fmaf(H[r][k], WD[k * 10 + c], acc);
        VD[r][c] = acc;
    }
    __syncthreads();
    if (tid < 128) {
        int r = tid >> 2, a = tid & 3;
        int row = r0 + r;
        if (row < NN) {
            float4 v = make_float4(VD[r][SMAT[a * 4 + 0]], VD[r][SMAT[a * 4 + 1]],
                                   VD[r][SMAT[a * 4 + 2]], VD[r][SMAT[a * 4 + 3]]);
            *(float4*)&S[(4 * row + a) * SDIM + 4 * row] = v;
        }
    }
}

// ---------------- edge kernel: round-3 compute; upper stores + ed_buf dump ----------------
__global__ __launch_bounds__(256) void k_edge(const int* __restrict__ ud,
                                              const float* __restrict__ g,
                                              const float* __restrict__ be1,
                                              const float* __restrict__ be2,
                                              const float* __restrict__ be3,
                                              const unsigned* __restrict__ W2F,
                                              const unsigned* __restrict__ W3F,
                                              float* __restrict__ S,
                                              float* __restrict__ ed_buf,
                                              int use_buf) {
    __shared__ float EDW[4][32][17];

    const int tid = threadIdx.x;
    const int wave = tid >> 6, lane = tid & 63;
    const int lrow = lane & 15, lgrp = lane >> 4;
    const int base_e = blockIdx.x * 128 + wave * 32;

    const int e0 = base_e + lrow;
    const int e1 = base_e + 16 + lrow;
    const int2 ij0 = ((const int2*)ud)[min(e0, NE - 1)];
    const int2 ij1 = ((const int2*)ud)[min(e1, NE - 1)];

    f32x4 b1a[2][2];
#pragma unroll
    for (int ks = 0; ks < 2; ks++) {
        b1a[ks][0] = *(const f32x4*)(be1 + ks * 32 + lgrp * 8);
        b1a[ks][1] = *(const f32x4*)(be1 + ks * 32 + lgrp * 8 + 4);
    }

    bf16x8 Uhi[2][2], Ulo[2][2];
#pragma unroll
    for (int nt = 0; nt < 2; nt++) {
        const int2 ij = nt ? ij1 : ij0;
        const float* gi = g + ij.x * 64;
        const float* gj = g + ij.y * 64;
#pragma unroll
        for (int ks = 0; ks < 2; ks++) {
            int kb = ks * 32 + lgrp * 8;
            f32x4 x0 = *(const f32x4*)(gi + kb);
            f32x4 x1 = *(const f32x4*)(gi + kb + 4);
            f32x4 y0 = *(const f32x4*)(gj + kb);
            f32x4 y1 = *(const f32x4*)(gj + kb + 4);
            float u[8];
#pragma unroll
            for (int e = 0; e < 4; e++) {
                u[e]     = lk(x0[e] + y0[e] + b1a[ks][0][e]);
                u[4 + e] = lk(x1[e] + y1[e] + b1a[ks][1][e]);
            }
            split8(u, Uhi[nt][ks], Ulo[nt][ks]);
        }
    }

    bf16x4 Vhi[4][2], Vlo[4][2];
#pragma unroll
    for (int mt = 0; mt < 4; mt++) {
        f32x4 acc[2];
#pragma unroll
        for (int nt = 0; nt < 2; nt++)
#pragma unroll
            for (int q = 0; q < 4; q++) acc[nt][q] = 0.f;
#pragma unroll
        for (int ks = 0; ks < 2; ks++) {
            bf16x8 Whi = *(const bf16x8*)(W2F + ((mt * 2 + ks) * 2 + 0) * 256 + lane * 4);
            bf16x8 Wlo = *(const bf16x8*)(W2F + ((mt * 2 + ks) * 2 + 1) * 256 + lane * 4);
#pragma unroll
            for (int nt = 0; nt < 2; nt++) {
                acc[nt] = __builtin_amdgcn_mfma_f32_16x16x32_bf16(Whi, Uhi[nt][ks], acc[nt], 0, 0, 0);
                acc[nt] = __builtin_amdgcn_mfma_f32_16x16x32_bf16(Wlo, Uhi[nt][ks], acc[nt], 0, 0, 0);
                acc[nt] = __builtin_amdgcn_mfma_f32_16x16x32_bf16(Whi, Ulo[nt][ks], acc[nt], 0, 0, 0);
            }
        }
        f32x4 b2 = *(const f32x4*)(be2 + mt * 16 + lgrp * 4);
#pragma unroll
        for (int nt = 0; nt < 2; nt++) {
            float v[4];
#pragma unroll
            for (int q = 0; q < 4; q++) v[q] = lk(acc[nt][q] + b2[q]);
            split4(v, Vhi[mt][nt], Vlo[mt][nt]);
        }
    }

    f32x4 acc3[2];
#pragma unroll
    for (int nt = 0; nt < 2; nt++)
#pragma unroll
        for (int q = 0; q < 4; q++) acc3[nt][q] = 0.f;
#pragma unroll
    for (int kb = 0; kb < 4; kb++) {
        bf16x4 W3h = *(const bf16x4*)(W3F + (kb * 2 + 0) * 128 + lane * 2);
        bf16x4 W3l = *(const bf16x4*)(W3F + (kb * 2 + 1) * 128 + lane * 2);
#pragma unroll
        for (int nt = 0; nt < 2; nt++) {
            acc3[nt] = mfma1616(W3h, Vhi[kb][nt], acc3[nt]);
            acc3[nt] = mfma1616(W3l, Vhi[kb][nt], acc3[nt]);
            acc3[nt] = mfma1616(W3h, Vlo[kb][nt], acc3[nt]);
        }
    }

    f32x4 b3 = *(const f32x4*)(be3 + lgrp * 4);
#pragma unroll
    for (int nt = 0; nt < 2; nt++) {
        const int e = nt ? e1 : e0;
        const int2 ij = nt ? ij1 : ij0;
        float ed[4];
#pragma unroll
        for (int q = 0; q < 4; q++) {
            ed[q] = acc3[nt][q] + b3[q];
            EDW[wave][nt * 16 + lrow][lgrp * 4 + q] = ed[q];
        }
        if (e < NE) {
            *(float4*)&S[(4 * ij.x + lgrp) * SDIM + 4 * ij.y] =
                make_float4(ed[0], ed[1], ed[2], ed[3]);
            if (use_buf)
                *(float4*)&ed_buf[e * 16 + lgrp * 4] =
                    make_float4(ed[0], ed[1], ed[2], ed[3]);
        }
    }

    if (!use_buf) {
        // round-3 proven lower-triangle (transposed) scattered stores
        const int le = lane & 31;
        const int lg2 = lane >> 5;
        const int eL = base_e + le;
        const int2 ijL = ((const int2*)ud)[min(eL, NE - 1)];
#pragma unroll
        for (int q = 0; q < 2; q++) {
            int a = lg2 * 2 + q;
            float4 v = make_float4(EDW[wave][le][a], EDW[wave][le][4 + a],
                                   EDW[wave][le][8 + a], EDW[wave][le][12 + a]);
            if (eL < NE) *(float4*)&S[(4 * ijL.y + a) * SDIM + 4 * ijL.x] = v;
        }
    }
}

// ---------------- k_low: lower-triangle rows, coalesced, from ed_buf ----------------
// WG b handles row-blocks J = b and J = 1199 - b (balanced: J + (1199-J) = 1199 cols each)
__global__ __launch_bounds__(256) void k_low(const float* __restrict__ ed_buf,
                                             float* __restrict__ S) {
    const int tid = threadIdx.x;
#pragma unroll
    for (int rep = 0; rep < 2; rep++) {
        const int J = rep ? (NN - 1 - (int)blockIdx.x) : (int)blockIdx.x;
        for (int i0 = 0; i0 < J; i0 += 256) {
            int i = i0 + tid;
            if (i < J) {
                int e = i * (NN - 1) - (i * (i + 1)) / 2 + (J - i - 1);
                const float* eb = ed_buf + e * 16;
                f32x4 q0 = *(const f32x4*)(eb);
                f32x4 q1 = *(const f32x4*)(eb + 4);
                f32x4 q2 = *(const f32x4*)(eb + 8);
                f32x4 q3 = *(const f32x4*)(eb + 12);
                // block(J,i) = ed^T : row a = (q0[a], q1[a], q2[a], q3[a])
                *(float4*)&S[(4 * J + 0) * SDIM + 4 * i] = make_float4(q0[0], q1[0], q2[0], q3[0]);
                *(float4*)&S[(4 * J + 1) * SDIM + 4 * i] = make_float4(q0[1], q1[1], q2[1], q3[1]);
                *(float4*)&S[(4 * J + 2) * SDIM + 4 * i] = make_float4(q0[2], q1[2], q2[2], q3[2]);
                *(float4*)&S[(4 * J + 3) * SDIM + 4 * i] = make_float4(q0[3], q1[3], q2[3], q3[3]);
            }
        }
    }
}

extern "C" void kernel_launch(void* const* d_in, const int* in_sizes, int n_in,
                              void* d_out, int out_size, void* d_ws, size_t ws_size,
                              hipStream_t stream) {
    const float* x   = (const float*)d_in[0];
    const int*   ud  = (const int*)d_in[3];
    const float* Wg1 = (const float*)d_in[4];
    const float* bg1 = (const float*)d_in[5];
    const float* Wg2 = (const float*)d_in[6];
    const float* bg2 = (const float*)d_in[7];
    const float* Wg3 = (const float*)d_in[8];
    const float* bg3 = (const float*)d_in[9];
    const float* Wn1 = (const float*)d_in[10];
    const float* bn1 = (const float*)d_in[11];
    const float* Wn2 = (const float*)d_in[12];
    const float* bn2 = (const float*)d_in[13];
    const float* Wn3 = (const float*)d_in[14];
    const float* bn3 = (const float*)d_in[15];
    const float* We1 = (const float*)d_in[16];
    const float* be1 = (const float*)d_in[17];
    const float* We2 = (const float*)d_in[18];
    const float* be2 = (const float*)d_in[19];
    const float* We3 = (const float*)d_in[20];
    const float* be3 = (const float*)d_in[21];

    float* out   = (float*)d_out;
    float* h_out = out;                 // 1200*64
    float* S     = out + 76800;         // 4800*4800

    float* ws  = (float*)d_ws;
    float* t1  = ws;                    // 38400
    float* t2  = ws + 38400;            // 38400
    float* t3  = ws + 76800;            // 76800
    float* g   = ws + 153600;           // 76800
    float* cs  = ws + 230400;           // 128
    unsigned* W2F = (unsigned*)(ws + 230528);  // 4096 u32
    unsigned* W3F = W2F + 4096;                // 1024 u32
    float* ed_buf = ws + 235648;               // NE*16 = 11,510,400 floats (46 MB)

    const size_t need = (size_t)(235648 + (size_t)NE * 16) * 4;
    const int use_buf = (ws_size >= need) ? 1 : 0;

    k_prep<<<4, 256, 0, stream>>>(We2, We3, W2F, W3F, cs);
    k_t1<<<38, 256, 0, stream>>>(x, Wg1, t1, cs);
    k_t2<<<38, 256, 0, stream>>>(t1, cs, bg1, Wg2, t2, cs + 32);
    k_t3<<<38, 256, 0, stream>>>(t2, cs + 32, bg2, Wg3, t3, cs + 64);
    k_g<<<38, 256, 0, stream>>>(t3, cs + 64, bg3, We1, h_out, g);
    k_edge<<<5621, 256, 0, stream>>>(ud, g, be1, be2, be3, W2F, W3F, S, ed_buf, use_buf);
    if (use_buf) k_low<<<600, 256, 0, stream>>>(ed_buf, S);
    k_vd<<<38, 256, 0, stream>>>(h_out, Wn1, bn1, Wn2, bn2, Wn3, bn3, S);
}

// Round 11
// 132.284 us; speedup vs baseline: 1.0569x; 1.0569x over previous
//
#include <hip/hip_runtime.h>

#define NN 1200
#define NE 719400
#define SDIM 4800

typedef __attribute__((ext_vector_type(8))) short bf16x8;
typedef __attribute__((ext_vector_type(4))) short bf16x4;
typedef __attribute__((ext_vector_type(4))) float f32x4;

static __device__ __constant__ int SMAT[16] = {0,1,2,3,1,4,5,6,2,5,7,8,3,6,8,9};

__device__ __forceinline__ float lk(float v) { return v >= 0.f ? v : 0.1f * v; }

#if __has_builtin(__builtin_amdgcn_mfma_f32_16x16x16bf16_1k)
__device__ __forceinline__ f32x4 mfma1616(bf16x4 a, bf16x4 b, f32x4 c) {
    return __builtin_amdgcn_mfma_f32_16x16x16bf16_1k(a, b, c, 0, 0, 0);
}
#else
__device__ __forceinline__ f32x4 mfma1616(bf16x4 a, bf16x4 b, f32x4 c) {
    asm volatile("v_mfma_f32_16x16x16_bf16 %0, %1, %2, %0\n\ts_nop 7\n\ts_nop 7"
                 : "+v"(c) : "v"(a), "v"(b));
    return c;
}
#endif

// split f32 -> bf16 hi (RNE) + bf16 lo (RNE of residual)  [rounds 2/3/8 proven bit-twiddle]
__device__ __forceinline__ void split8(const float* u, bf16x8& hi, bf16x8& lo) {
#pragma unroll
    for (int e = 0; e < 8; e++) {
        unsigned x = __float_as_uint(u[e]);
        unsigned r = x + 0x7FFFu + ((x >> 16) & 1u);
        hi[e] = (short)(r >> 16);
        float hf = __uint_as_float(r & 0xFFFF0000u);
        float s = u[e] - hf;
        unsigned v = __float_as_uint(s);
        unsigned w = v + 0x7FFFu + ((v >> 16) & 1u);
        lo[e] = (short)(w >> 16);
    }
}

__device__ __forceinline__ void split4(const float* u, bf16x4& hi, bf16x4& lo) {
#pragma unroll
    for (int e = 0; e < 4; e++) {
        unsigned x = __float_as_uint(u[e]);
        unsigned r = x + 0x7FFFu + ((x >> 16) & 1u);
        hi[e] = (short)(r >> 16);
        float hf = __uint_as_float(r & 0xFFFF0000u);
        float s = u[e] - hf;
        unsigned v = __float_as_uint(s);
        unsigned w = v + 0x7FFFu + ((v >> 16) & 1u);
        lo[e] = (short)(w >> 16);
    }
}

__device__ __forceinline__ uint2 split2(float a0, float a1) {
    unsigned u0 = __float_as_uint(a0), u1 = __float_as_uint(a1);
    unsigned r0 = u0 + 0x7FFFu + ((u0 >> 16) & 1u);
    unsigned r1 = u1 + 0x7FFFu + ((u1 >> 16) & 1u);
    float h0 = __uint_as_float(r0 & 0xFFFF0000u);
    float h1 = __uint_as_float(r1 & 0xFFFF0000u);
    float s0 = a0 - h0, s1 = a1 - h1;
    unsigned v0 = __float_as_uint(s0), v1 = __float_as_uint(s1);
    unsigned t0 = v0 + 0x7FFFu + ((v0 >> 16) & 1u);
    unsigned t1 = v1 + 0x7FFFu + ((v1 >> 16) & 1u);
    unsigned hi = (r0 >> 16) | (r1 & 0xFFFF0000u);
    unsigned lo = (t0 >> 16) | (t1 & 0xFFFF0000u);
    return make_uint2(hi, lo);
}

// ---------------- prep: We2^T A-frags (16x16x32), We3^T A-frags (16x16x16), cs zero ----
__global__ void k_prep(const float* __restrict__ We2, const float* __restrict__ We3,
                       unsigned* __restrict__ W2F, unsigned* __restrict__ W3F,
                       float* __restrict__ cs) {
    int t = blockIdx.x * 256 + threadIdx.x;
    if (t < 512) {
        int lane = t & 63, ks = (t >> 6) & 1, mt = t >> 7;
        int m = mt * 16 + (lane & 15);
        int kb = ks * 32 + (lane >> 4) * 8;
        unsigned hi[4], lo[4];
#pragma unroll
        for (int p = 0; p < 4; p++) {
            float a0 = We2[(kb + 2 * p) * 64 + m];
            float a1 = We2[(kb + 2 * p + 1) * 64 + m];
            uint2 hl = split2(a0, a1);
            hi[p] = hl.x; lo[p] = hl.y;
        }
        *(uint4*)(W2F + ((mt * 2 + ks) * 2 + 0) * 256 + lane * 4) = make_uint4(hi[0], hi[1], hi[2], hi[3]);
        *(uint4*)(W2F + ((mt * 2 + ks) * 2 + 1) * 256 + lane * 4) = make_uint4(lo[0], lo[1], lo[2], lo[3]);
    } else if (t < 768) {
        int q = t - 512;
        int lane = q & 63, kb = q >> 6;
        int c = lane & 15;
        int k0 = kb * 16 + (lane >> 4) * 4;
        unsigned hi[2], lo[2];
#pragma unroll
        for (int p = 0; p < 2; p++) {
            float a0 = We3[(k0 + 2 * p) * 16 + c];
            float a1 = We3[(k0 + 2 * p + 1) * 16 + c];
            uint2 hl = split2(a0, a1);
            hi[p] = hl.x; lo[p] = hl.y;
        }
        *(uint2*)(W3F + (kb * 2 + 0) * 128 + lane * 2) = make_uint2(hi[0], hi[1]);
        *(uint2*)(W3F + (kb * 2 + 1) * 128 + lane * 2) = make_uint2(lo[0], lo[1]);
    } else if (t < 896) {
        cs[t - 768] = 0.f;
    }
}

// ---------------- GCN stage 1 ----------------
__global__ __launch_bounds__(256) void k_t1(const float* __restrict__ x,
                                            const float* __restrict__ Wg1,
                                            float* __restrict__ t1,
                                            float* __restrict__ cs1) {
    int T = blockIdx.x * 256 + threadIdx.x;
    int c = T & 31, rs = T >> 5;
    float w[6];
#pragma unroll
    for (int k = 0; k < 6; k++) w[k] = Wg1[k * 32 + c];
    float loc = 0.f;
    for (int r = rs; r < NN; r += 304) {
        float acc = 0.f;
#pragma unroll
        for (int k = 0; k < 6; k++) acc = fmaf(x[r * 16 + k], w[k], acc);
        t1[r * 32 + c] = acc;
        loc += acc;
    }
    atomicAdd(&cs1[c], loc);
}

// ---------------- GCN stage 2 ----------------
__global__ __launch_bounds__(256) void k_t2(const float* __restrict__ t1,
                                            const float* __restrict__ cs1,
                                            const float* __restrict__ bg1,
                                            const float* __restrict__ Wg2,
                                            float* __restrict__ t2,
                                            float* __restrict__ cs2) {
    int T = blockIdx.x * 256 + threadIdx.x;
    int c = T & 31, rs = T >> 5;
    const float inv = 1.0f / 1199.0f;
    float p[32], w[32];
#pragma unroll
    for (int k = 0; k < 32; k++) {
        p[k] = fmaf(cs1[k], inv, bg1[k]);
        w[k] = Wg2[k * 32 + c];
    }
    float loc = 0.f;
    for (int r = rs; r < NN; r += 304) {
        float acc = 0.f;
#pragma unroll
        for (int k = 0; k < 32; k++) {
            float h = lk(fmaf(-t1[r * 32 + k], inv, p[k]));
            acc = fmaf(h, w[k], acc);
        }
        t2[r * 32 + c] = acc;
        loc += acc;
    }
    atomicAdd(&cs2[c], loc);
}

// ---------------- GCN stage 3 ----------------
__global__ __launch_bounds__(256) void k_t3(const float* __restrict__ t2,
                                            const float* __restrict__ cs2,
                                            const float* __restrict__ bg2,
                                            const float* __restrict__ Wg3,
                                            float* __restrict__ t3,
                                            float* __restrict__ cs3) {
    int T = blockIdx.x * 256 + threadIdx.x;
    int c = T & 63, rs = T >> 6;
    const float inv = 1.0f / 1199.0f;
    float p[32], w[32];
#pragma unroll
    for (int k = 0; k < 32; k++) {
        p[k] = fmaf(cs2[k], inv, bg2[k]);
        w[k] = Wg3[k * 64 + c];
    }
    float loc = 0.f;
    for (int r = rs; r < NN; r += 152) {
        float acc = 0.f;
#pragma unroll
        for (int k = 0; k < 32; k++) {
            float h = lk(fmaf(-t2[r * 32 + k], inv, p[k]));
            acc = fmaf(h, w[k], acc);
        }
        t3[r * 64 + c] = acc;
        loc += acc;
    }
    atomicAdd(&cs3[c], loc);
}

// ---------------- k_g: h = GCN3 output, g = h @ We1 ----------------
__global__ __launch_bounds__(256) void k_g(const float* __restrict__ t3,
                                           const float* __restrict__ cs3,
                                           const float* __restrict__ bg3,
                                           const float* __restrict__ We1,
                                           float* __restrict__ h_out,
                                           float* __restrict__ g_out) {
    __shared__ float H[32][65];
    __shared__ float W[4096];
    const int tid = threadIdx.x;
    const int r0 = blockIdx.x * 32;
    const float inv = 1.0f / 1199.0f;

    for (int t = tid; t < 1024; t += 256) ((float4*)W)[t] = ((const float4*)We1)[t];
    for (int t = tid; t < 2048; t += 256) {
        int i = t >> 6, c = t & 63;
        int row = r0 + i;
        float v = 0.f;
        if (row < NN) {
            v = fmaf(cs3[c] - t3[row * 64 + c], inv, bg3[c]);
            h_out[row * 64 + c] = v;
        }
        H[i][c] = v;
    }
    __syncthreads();

    int rg = tid >> 3, cg = tid & 7;
    float acc[8] = {};
#pragma unroll 8
    for (int k = 0; k < 64; k++) {
        float a = H[rg][k];
        float4 b0 = *(const float4*)&W[k * 64 + cg * 8];
        float4 b1 = *(const float4*)&W[k * 64 + cg * 8 + 4];
        acc[0] = fmaf(a, b0.x, acc[0]); acc[1] = fmaf(a, b0.y, acc[1]);
        acc[2] = fmaf(a, b0.z, acc[2]); acc[3] = fmaf(a, b0.w, acc[3]);
        acc[4] = fmaf(a, b1.x, acc[4]); acc[5] = fmaf(a, b1.y, acc[5]);
        acc[6] = fmaf(a, b1.z, acc[6]); acc[7] = fmaf(a, b1.w, acc[7]);
    }
    int row = r0 + rg;
    if (row < NN) {
        *(float4*)&g_out[row * 64 + cg * 8]     = make_float4(acc[0], acc[1], acc[2], acc[3]);
        *(float4*)&g_out[row * 64 + cg * 8 + 4] = make_float4(acc[4], acc[5], acc[6], acc[7]);
    }
}

// ---------------- k_vd: node MLP + diagonal Vsym blocks -> S ----------------
__global__ __launch_bounds__(256) void k_vd(const float* __restrict__ h,
                                            const float* __restrict__ Wn1, const float* __restrict__ bn1,
                                            const float* __restrict__ Wn2, const float* __restrict__ bn2,
                                            const float* __restrict__ Wn3, const float* __restrict__ bn3,
                                            float* __restrict__ S) {
    __shared__ float H[32][65];
    __shared__ float N1[32][65];
    __shared__ float WB[4096];
    __shared__ float WC[4096];
    __shared__ float WD[640];
    __shared__ float VD[32][12];
    __shared__ float sb1[64], sb2[64], sb3[16];

    const int tid = threadIdx.x;
    const int r0 = blockIdx.x * 32;

    for (int t = tid; t < 1024; t += 256) {
        ((float4*)WB)[t] = ((const float4*)Wn1)[t];
        ((float4*)WC)[t] = ((const float4*)Wn2)[t];
    }
    for (int t = tid; t < 640; t += 256) WD[t] = Wn3[t];
    if (tid < 64) { sb1[tid] = bn1[tid]; sb2[tid] = bn2[tid]; }
    if (tid < 10) sb3[tid] = bn3[tid];

    for (int t = tid; t < 2048; t += 256) {
        int i = t >> 6, c = t & 63;
        int row = r0 + i;
        H[i][c] = (row < NN) ? h[row * 64 + c] : 0.f;
    }
    __syncthreads();

    int rg = tid >> 3, cg = tid & 7;
    {
        float acc[8] = {};
#pragma unroll 8
        for (int k = 0; k < 64; k++) {
            float a = H[rg][k];
            float4 b0 = *(const float4*)&WB[k * 64 + cg * 8];
            float4 b1 = *(const float4*)&WB[k * 64 + cg * 8 + 4];
            acc[0] = fmaf(a, b0.x, acc[0]); acc[1] = fmaf(a, b0.y, acc[1]);
            acc[2] = fmaf(a, b0.z, acc[2]); acc[3] = fmaf(a, b0.w, acc[3]);
            acc[4] = fmaf(a, b1.x, acc[4]); acc[5] = fmaf(a, b1.y, acc[5]);
            acc[6] = fmaf(a, b1.z, acc[6]); acc[7] = fmaf(a, b1.w, acc[7]);
        }
#pragma unroll
        for (int q = 0; q < 8; q++) N1[rg][cg * 8 + q] = lk(acc[q] + sb1[cg * 8 + q]);
    }
    __syncthreads();
    {
        float acc[8] = {};
#pragma unroll 8
        for (int k = 0; k < 64; k++) {
            float a = N1[rg][k];
            float4 b0 = *(const float4*)&WC[k * 64 + cg * 8];
            float4 b1 = *(const float4*)&WC[k * 64 + cg * 8 + 4];
            acc[0] = fmaf(a, b0.x, acc[0]); acc[1] = fmaf(a, b0.y, acc[1]);
            acc[2] = fmaf(a, b0.z, acc[2]); acc[3] = fmaf(a, b0.w, acc[3]);
            acc[4] = fmaf(a, b1.x, acc[4]); acc[5] = fmaf(a, b1.y, acc[5]);
            acc[6] = fmaf(a, b1.z, acc[6]); acc[7] = fmaf(a, b1.w, acc[7]);
        }
#pragma unroll
        for (int q = 0; q < 8; q++) H[rg][cg * 8 + q] = lk(acc[q] + sb2[cg * 8 + q]);
    }
    __syncthreads();
    for (int t = tid; t < 320; t += 256) {
        int r = t / 10, c = t % 10;
        float acc = sb3[c];
        for (int k = 0; k < 64; k++) acc = fmaf(H[r][k], WD[k * 10 + c], acc);
        VD[r][c] = acc;
    }
    __syncthreads();
    if (tid < 128) {
        int r = tid >> 2, a = tid & 3;
        int row = r0 + r;
        if (row < NN) {
            float4 v = make_float4(VD[r][SMAT[a * 4 + 0]], VD[r][SMAT[a * 4 + 1]],
                                   VD[r][SMAT[a * 4 + 2]], VD[r][SMAT[a * 4 + 3]]);
            *(float4*)&S[(4 * row + a) * SDIM + 4 * row] = v;
        }
    }
}

// ---------------- edge kernel: round-8 compute verbatim; upper-triangle stores only ----
__global__ __launch_bounds__(256) void k_edge(const int* __restrict__ ud,
                                              const float* __restrict__ g,
                                              const float* __restrict__ be1,
                                              const float* __restrict__ be2,
                                              const float* __restrict__ be3,
                                              const unsigned* __restrict__ W2F,
                                              const unsigned* __restrict__ W3F,
                                              float* __restrict__ S) {
    const int tid = threadIdx.x;
    const int wave = tid >> 6, lane = tid & 63;
    const int lrow = lane & 15, lgrp = lane >> 4;
    const int base_e = blockIdx.x * 128 + wave * 32;

    const int e0 = base_e + lrow;
    const int e1 = base_e + 16 + lrow;
    const int2 ij0 = ((const int2*)ud)[min(e0, NE - 1)];
    const int2 ij1 = ((const int2*)ud)[min(e1, NE - 1)];

    f32x4 b1a[2][2];
#pragma unroll
    for (int ks = 0; ks < 2; ks++) {
        b1a[ks][0] = *(const f32x4*)(be1 + ks * 32 + lgrp * 8);
        b1a[ks][1] = *(const f32x4*)(be1 + ks * 32 + lgrp * 8 + 4);
    }

    bf16x8 Uhi[2][2], Ulo[2][2];
#pragma unroll
    for (int nt = 0; nt < 2; nt++) {
        const int2 ij = nt ? ij1 : ij0;
        const float* gi = g + ij.x * 64;
        const float* gj = g + ij.y * 64;
#pragma unroll
        for (int ks = 0; ks < 2; ks++) {
            int kb = ks * 32 + lgrp * 8;
            f32x4 x0 = *(const f32x4*)(gi + kb);
            f32x4 x1 = *(const f32x4*)(gi + kb + 4);
            f32x4 y0 = *(const f32x4*)(gj + kb);
            f32x4 y1 = *(const f32x4*)(gj + kb + 4);
            float u[8];
#pragma unroll
            for (int e = 0; e < 4; e++) {
                u[e]     = lk(x0[e] + y0[e] + b1a[ks][0][e]);
                u[4 + e] = lk(x1[e] + y1[e] + b1a[ks][1][e]);
            }
            split8(u, Uhi[nt][ks], Ulo[nt][ks]);
        }
    }

    bf16x4 Vhi[4][2], Vlo[4][2];
#pragma unroll
    for (int mt = 0; mt < 4; mt++) {
        f32x4 acc[2];
#pragma unroll
        for (int nt = 0; nt < 2; nt++)
#pragma unroll
            for (int q = 0; q < 4; q++) acc[nt][q] = 0.f;
#pragma unroll
        for (int ks = 0; ks < 2; ks++) {
            bf16x8 Whi = *(const bf16x8*)(W2F + ((mt * 2 + ks) * 2 + 0) * 256 + lane * 4);
            bf16x8 Wlo = *(const bf16x8*)(W2F + ((mt * 2 + ks) * 2 + 1) * 256 + lane * 4);
#pragma unroll
            for (int nt = 0; nt < 2; nt++) {
                acc[nt] = __builtin_amdgcn_mfma_f32_16x16x32_bf16(Whi, Uhi[nt][ks], acc[nt], 0, 0, 0);
                acc[nt] = __builtin_amdgcn_mfma_f32_16x16x32_bf16(Wlo, Uhi[nt][ks], acc[nt], 0, 0, 0);
                acc[nt] = __builtin_amdgcn_mfma_f32_16x16x32_bf16(Whi, Ulo[nt][ks], acc[nt], 0, 0, 0);
            }
        }
        f32x4 b2 = *(const f32x4*)(be2 + mt * 16 + lgrp * 4);
#pragma unroll
        for (int nt = 0; nt < 2; nt++) {
            float v[4];
#pragma unroll
            for (int q = 0; q < 4; q++) v[q] = lk(acc[nt][q] + b2[q]);
            split4(v, Vhi[mt][nt], Vlo[mt][nt]);
        }
    }

    f32x4 acc3[2];
#pragma unroll
    for (int nt = 0; nt < 2; nt++)
#pragma unroll
        for (int q = 0; q < 4; q++) acc3[nt][q] = 0.f;
#pragma unroll
    for (int kb = 0; kb < 4; kb++) {
        bf16x4 W3h = *(const bf16x4*)(W3F + (kb * 2 + 0) * 128 + lane * 2);
        bf16x4 W3l = *(const bf16x4*)(W3F + (kb * 2 + 1) * 128 + lane * 2);
#pragma unroll
        for (int nt = 0; nt < 2; nt++) {
            acc3[nt] = mfma1616(W3h, Vhi[kb][nt], acc3[nt]);
            acc3[nt] = mfma1616(W3l, Vhi[kb][nt], acc3[nt]);
            acc3[nt] = mfma1616(W3h, Vlo[kb][nt], acc3[nt]);
        }
    }

    f32x4 b3 = *(const f32x4*)(be3 + lgrp * 4);
#pragma unroll
    for (int nt = 0; nt < 2; nt++) {
        const int e = nt ? e1 : e0;
        const int2 ij = nt ? ij1 : ij0;
        if (e < NE) {
            *(float4*)&S[(4 * ij.x + lgrp) * SDIM + 4 * ij.y] =
                make_float4(acc3[nt][0] + b3[0], acc3[nt][1] + b3[1],
                            acc3[nt][2] + b3[2], acc3[nt][3] + b3[3]);
        }
    }
}

// ---------------- k_tr: tiled in-place transpose upper -> lower (64x64 tiles) ----------
// 4800/64 = 75 exact tiles per side; 75*76/2 = 2850 WGs (ti <= tj). LDS 16.6 KB.
__global__ __launch_bounds__(256) void k_tr(float* __restrict__ S) {
    __shared__ float T[64][65];
    const int tid = threadIdx.x;

    int b = blockIdx.x;
    int ti = 0;
    while (b >= 75 - ti) { b -= 75 - ti; ti++; }
    const int tj = ti + b;
    const int r0 = ti * 64, c0 = tj * 64;

    // read: 64 rows x 16 float4-cols
#pragma unroll
    for (int it = 0; it < 4; ++it) {
        int idx = tid + it * 256;
        int rr = idx >> 4, cc4 = idx & 15;
        float4 v = *(const float4*)&S[(r0 + rr) * SDIM + c0 + cc4 * 4];
        T[rr][cc4 * 4 + 0] = v.x; T[rr][cc4 * 4 + 1] = v.y;
        T[rr][cc4 * 4 + 2] = v.z; T[rr][cc4 * 4 + 3] = v.w;
    }
    __syncthreads();

    // write: out row c0+cc, out cols r0+rr4*4..+3; only strictly-upper source blocks
#pragma unroll
    for (int it = 0; it < 4; ++it) {
        int idx = tid + it * 256;
        int cc = idx >> 4, rr4 = idx & 15;
        int br = (r0 >> 2) + rr4;        // source 4x4-block row
        int bc = (c0 >> 2) + (cc >> 2);  // source 4x4-block col
        if (bc > br) {
            float4 w = make_float4(T[rr4 * 4 + 0][cc], T[rr4 * 4 + 1][cc],
                                   T[rr4 * 4 + 2][cc], T[rr4 * 4 + 3][cc]);
            *(float4*)&S[(c0 + cc) * SDIM + r0 + rr4 * 4] = w;
        }
    }
}

extern "C" void kernel_launch(void* const* d_in, const int* in_sizes, int n_in,
                              void* d_out, int out_size, void* d_ws, size_t ws_size,
                              hipStream_t stream) {
    const float* x   = (const float*)d_in[0];
    const int*   ud  = (const int*)d_in[3];
    const float* Wg1 = (const float*)d_in[4];
    const float* bg1 = (const float*)d_in[5];
    const float* Wg2 = (const float*)d_in[6];
    const float* bg2 = (const float*)d_in[7];
    const float* Wg3 = (const float*)d_in[8];
    const float* bg3 = (const float*)d_in[9];
    const float* Wn1 = (const float*)d_in[10];
    const float* bn1 = (const float*)d_in[11];
    const float* Wn2 = (const float*)d_in[12];
    const float* bn2 = (const float*)d_in[13];
    const float* Wn3 = (const float*)d_in[14];
    const float* bn3 = (const float*)d_in[15];
    const float* We1 = (const float*)d_in[16];
    const float* be1 = (const float*)d_in[17];
    const float* We2 = (const float*)d_in[18];
    const float* be2 = (const float*)d_in[19];
    const float* We3 = (const float*)d_in[20];
    const float* be3 = (const float*)d_in[21];

    float* out   = (float*)d_out;
    float* h_out = out;                 // 1200*64
    float* S     = out + 76800;         // 4800*4800

    float* ws  = (float*)d_ws;
    float* t1  = ws;                    // 38400
    float* t2  = ws + 38400;            // 38400
    float* t3  = ws + 76800;            // 76800
    float* g   = ws + 153600;           // 76800
    float* cs  = ws + 230400;           // 128
    unsigned* W2F = (unsigned*)(ws + 230528);  // 4096 u32
    unsigned* W3F = W2F + 4096;                // 1024 u32

    k_prep<<<4, 256, 0, stream>>>(We2, We3, W2F, W3F, cs);
    k_t1<<<38, 256, 0, stream>>>(x, Wg1, t1, cs);
    k_t2<<<38, 256, 0, stream>>>(t1, cs, bg1, Wg2, t2, cs + 32);
    k_t3<<<38, 256, 0, stream>>>(t2, cs + 32, bg2, Wg3, t3, cs + 64);
    k_g<<<38, 256, 0, stream>>>(t3, cs + 64, bg3, We1, h_out, g);
    k_edge<<<5621, 256, 0, stream>>>(ud, g, be1, be2, be3, W2F, W3F, S);
    k_tr<<<2850, 256, 0, stream>>>(S);
    k_vd<<<38, 256, 0, stream>>>(h_out, Wn1, bn1, Wn2, bn2, Wn3, bn3, S);
}